// Round 8
// baseline (177.288 us; speedup 1.0000x reference)
//
#include <hip/hip_runtime.h>
#include <stdint.h>

// VQ-VAE nearest-codeword quantization, MI355X (gfx950).
// M=16384 rows, D=256 dims, K=8192 codewords.
// argmin_k ||x-c_k||^2 == argmin_k ( ||c_k||^2 - 2 x.c_k )
//
// R15: R14 (proven-best composition, 175.3us) + two compiler-level VALU/stall
// cuts in vq_main. The 2-buffer/__syncthreads skeleton, DMA issue points,
// XOR swizzle, epilogue and numerics are UNCHANGED (R13 proved sync-structure
// grafts catastrophically regress; this round touches neither barriers nor
// waitcnts):
//  1. 8-stage loop fully unrolled + ALL 32 c2 values preloaded to registers
//     before the main loop (static-indexed cvv[8][4] -> VGPRs). R14 issued
//     the 4 c2 loads AFTER each stage's __syncthreads (compiler cannot hoist
//     loads over a barrier) and consumed them ~10cy later for acc-init:
//     ~200-400cy exposed latency x8 stages, now zero.
//  2. B fragment assembled with __builtin_shufflevector(lo,hi) instead of
//     element-wise inserts -> allocator can place lo/hi adjacent and elide
//     up to 16 v_mov per 16-col group.
// merge: serial-rescore (R14-proven). prep unchanged.
// Refuted levers (counter evidence): no-LDS streaming (R9-R11), launch_bounds
// (256,4) (R12 spill), counted vmcnt+raw barrier (R13 HBM thrash).
// Numerics, proven absmax 0.0: forced-RTNE fp8, Ap=-2x with c2 pre-loaded in
// the MFMA C operand, med3 sorted top-4 per 512-col split, EPS=20 fp64
// rescore, ties -> smaller index like np.argmin.

#define M_ROWS 16384
#define D_DIM  256
#define K_CB   8192
#define NSPLIT 16           // 512 codewords per split
#define CHUNK  64           // cols staged per barrier
#define EPS 20.0f

typedef float f32x4 __attribute__((ext_vector_type(4)));
typedef int   int4v __attribute__((ext_vector_type(4)));
typedef int   int8v __attribute__((ext_vector_type(8)));

__device__ __forceinline__ uint32_t umin32(uint32_t a, uint32_t b) { return a < b ? a : b; }
__device__ __forceinline__ uint32_t umax32(uint32_t a, uint32_t b) { return a > b ? a : b; }

// packed values are positive normal floats: float compare == uint compare
__device__ __forceinline__ uint32_t fmin32(uint32_t a, uint32_t b) {
  return __float_as_uint(fminf(__uint_as_float(a), __uint_as_float(b)));
}
__device__ __forceinline__ uint32_t fmed32(uint32_t a, uint32_t b, uint32_t c) {
  return __float_as_uint(__builtin_amdgcn_fmed3f(
      __uint_as_float(a), __uint_as_float(b), __uint_as_float(c)));
}

__device__ __forceinline__ void gld_lds16(const void* g, void* l) {
  // async global->LDS, 16B/lane; LDS dest is wave-uniform base + lane*16.
  __builtin_amdgcn_global_load_lds((__attribute__((address_space(1))) void*)g,
                                   (__attribute__((address_space(3))) void*)l,
                                   16, 0, 0);
}

// round f32 to 3 mantissa bits, RTNE (carry into exponent handled by the add)
__device__ __forceinline__ float rtne3(float f) {
  uint32_t u = __float_as_uint(f);
  u = (u + 0x0007FFFFu + ((u >> 20) & 1u)) & 0xFFF00000u;
  return __uint_as_float(u);
}

__device__ __forceinline__ uint32_t fp8x4(const f32x4 v) {
  // pre-rounded values are exactly representable -> intrinsic is exact
  int p = __builtin_amdgcn_cvt_pk_fp8_f32(rtne3(v[0]), rtne3(v[1]), 0, false);
  p = __builtin_amdgcn_cvt_pk_fp8_f32(rtne3(v[2]), rtne3(v[3]), p, true);
  return (uint32_t)p;
}

// -- prep: x -> Ap fp8(-2x) + out_ze ; cb -> Bp fp8 + c2s = ||c||^2+1024 ----
__global__ __launch_bounds__(256) void prep(const float* __restrict__ x,
                                            const float* __restrict__ cb,
                                            uint8_t* __restrict__ Ap,
                                            uint8_t* __restrict__ Bp,
                                            float* __restrict__ c2s,
                                            float* __restrict__ out_ze) {
  const int w = threadIdx.x >> 6, lane = threadIdx.x & 63;
  if (blockIdx.x < M_ROWS / 4) {
    const int row = blockIdx.x * 4 + w;                 // one wave per x row
    const f32x4 v = *(const f32x4*)(x + (size_t)row * D_DIM + lane * 4);
    // store -2x: exact (sign+exponent), q(-2x)q(c) == -2 q(x)q(c) bit-exact,
    // so the EPS error bound is unchanged. |2x| <= ~11 << 448 (e4m3 max).
    f32x4 nv;
#pragma unroll
    for (int t = 0; t < 4; ++t) nv[t] = -2.0f * v[t];
    *(uint32_t*)(Ap + (size_t)row * D_DIM + lane * 4) = fp8x4(nv);
    *(f32x4*)(out_ze + (size_t)row * D_DIM + lane * 4) = v;   // identity encoder
  } else {
    const int row = (blockIdx.x - M_ROWS / 4) * 4 + w;  // one wave per codeword
    const f32x4 v = *(const f32x4*)(cb + (size_t)row * D_DIM + lane * 4);
    *(uint32_t*)(Bp + (size_t)row * D_DIM + lane * 4) = fp8x4(v);
    double s = 0.0;
#pragma unroll
    for (int t = 0; t < 4; ++t) s += (double)v[t] * (double)v[t];
#pragma unroll
    for (int m = 1; m < 64; m <<= 1) s += __shfl_xor(s, m, 64);
    if (lane == 0) c2s[row] = (float)s + 1024.0f;       // pre-shifted: s>0 packing
  }
}

// ---- main: fp8 K=256 GEMM, DMA-pipelined LDS B, fused packed top-4/split ----
__global__ __launch_bounds__(256, 3) void vq_main(const uint8_t* __restrict__ Ap,
                                                  const uint8_t* __restrict__ Bp,
                                                  const float* __restrict__ c2s,
                                                  uint4* __restrict__ part) {
  __shared__ uint8_t Bs[2][CHUNK * D_DIM];   // 2 x 16 KB, chunk-swizzled

  const int w    = threadIdx.x >> 6;
  const int lane = threadIdx.x & 63;
  const int fr   = lane & 15;         // frag m/n index
  const int fq   = lane >> 4;         // frag k-quarter (32 contiguous bytes)

  const int rowBase = blockIdx.x * 128 + w * 32;        // wave owns 32 rows
  const int colBase = blockIdx.y * 512;                 // block owns one split

  // A fragments (-2x) for the whole kernel
  int8v af[2][2];
  {
    const uint8_t* ab = Ap + (size_t)(rowBase + fr) * D_DIM + fq * 32;
#pragma unroll
    for (int i = 0; i < 2; ++i)
#pragma unroll
      for (int kh = 0; kh < 2; ++kh)
        af[i][kh] = *(const int8v*)(ab + (size_t)(i * 16) * D_DIM + kh * 128);
  }

  // stage-invariant DMA offsets: row rr = ii*4+dRow within the wave's 16 rows;
  // phys 16B chunk p of row n holds logical chunk p^(n&15), applied on the
  // GLOBAL source address (gld dest is wave-uniform base + lane*16).
  const int dRow = lane >> 4;
  const int dChk = lane & 15;
  int goff[4];
#pragma unroll
  for (int ii = 0; ii < 4; ++ii) {
    const int rr = ii * 4 + dRow;                       // == row & 15
    goff[ii] = rr * D_DIM + ((dChk ^ rr) << 4);
  }

#define STAGE_DMA(c, buf)                                                      \
  {                                                                            \
    const uint8_t* gb = Bp + ((size_t)(colBase + (c) * CHUNK + w * 16) << 8);  \
    uint8_t* lb = &Bs[buf][w * 16 * D_DIM] + lane * 16;                        \
    _Pragma("unroll")                                                          \
    for (int ii = 0; ii < 4; ++ii)                                             \
      gld_lds16(gb + goff[ii], lb + ii * 4 * D_DIM);                           \
  }

  // sorted top-4 per slot [i][r], packed ((s+1024) bits & ~511) | col9
  uint32_t t1[2][4], t2[2][4], t3[2][4], t4[2][4];
#pragma unroll
  for (int i = 0; i < 2; ++i)
#pragma unroll
    for (int r = 0; r < 4; ++r) {
      t1[i][r] = 0x7f7ffe00u; t2[i][r] = 0x7f7ffe00u;
      t3[i][r] = 0x7f7ffe00u; t4[i][r] = 0x7f7ffe00u;
    }

  // preload ALL c2 values for this split into registers BEFORE the main loop:
  // removes 8x post-barrier load-latency exposure (loads can't be hoisted
  // across __syncthreads by the compiler). Static indices -> VGPRs (rule #20).
  const float* c2p = c2s + colBase + fr;
  float cvv[8][4];
#pragma unroll
  for (int c = 0; c < 8; ++c)
#pragma unroll
    for (int jj = 0; jj < 4; ++jj)
      cvv[c][jj] = c2p[c * CHUNK + jj * 16];

  const int y0 = (fq * 2) << 4;                         // logical 32B k-quarter

  STAGE_DMA(0, 0);

#pragma unroll
  for (int c = 0; c < 512 / CHUNK; ++c) {               // 8 stages, unrolled
    __syncthreads();              // DMA[c] landed (issued a full stage ago)
    if (c < 512 / CHUNK - 1) STAGE_DMA(c + 1, (c + 1) & 1);

    const uint8_t* bsb = Bs[c & 1];
    const int cb0 = c * CHUNK;

#pragma unroll
    for (int jj = 0; jj < 4; ++jj) {                    // 4 col-frags of 16
      const uint8_t* bp = bsb + (jj * 16 + fr) * D_DIM;
      const float cv = cvv[c][jj];
      f32x4 acc[2];
      acc[0] = (f32x4){cv, cv, cv, cv};                 // c2 pre-loaded into C
      acc[1] = (f32x4){cv, cv, cv, cv};
#pragma unroll
      for (int kh = 0; kh < 2; ++kh) {
        const int y = (y0 ^ (fr << 4)) ^ (kh << 7);     // ((L0^fr)<<4)
        const int4v lo = *(const int4v*)(bp + y);
        const int4v hi = *(const int4v*)(bp + (y ^ 16));
        const int8v bf = __builtin_shufflevector(lo, hi, 0, 1, 2, 3, 4, 5, 6, 7);
#pragma unroll
        for (int i = 0; i < 2; ++i)
          acc[i] = __builtin_amdgcn_mfma_scale_f32_16x16x128_f8f6f4(
              af[i][kh], bf, acc[i], 0, 0,       // cbsz=fp8, blgp=fp8
              0, 0x7f7f7f7f, 0, 0x7f7f7f7f);     // unit E8M0 scales
      }
      // epilogue: acc == s = (1024+c2) - 2*cross; pack; med3 top-4 insert
      const int col9 = cb0 + jj * 16 + fr;
#pragma unroll
      for (int i = 0; i < 2; ++i)
#pragma unroll
        for (int r = 0; r < 4; ++r) {
          const uint32_t p =
              (__float_as_uint(acc[i][r]) & ~511u) | (uint32_t)col9;
          const uint32_t o1 = t1[i][r], o2 = t2[i][r];
          const uint32_t o3 = t3[i][r], o4 = t4[i][r];
          t1[i][r] = fmin32(p, o1);                 // 4 independent ops,
          t2[i][r] = fmed32(p, o1, o2);             // no serial chain
          t3[i][r] = fmed32(p, o2, o3);
          t4[i][r] = fmed32(p, o3, o4);
        }
    }
  }

  // cross-fr bitonic merge (lanes with same fq hold the same rows, disjoint
  // cols); lane fr==0 of each fq then stores its rows' top-4 directly.
#pragma unroll
  for (int i = 0; i < 2; ++i)
#pragma unroll
    for (int r = 0; r < 4; ++r) {
      uint32_t a1 = t1[i][r], a2 = t2[i][r], a3 = t3[i][r], a4 = t4[i][r];
#pragma unroll
      for (int m = 1; m < 16; m <<= 1) {
        const uint32_t b1 = __shfl_xor(a1, m, 64);
        const uint32_t b2 = __shfl_xor(a2, m, 64);
        const uint32_t b3 = __shfl_xor(a3, m, 64);
        const uint32_t b4 = __shfl_xor(a4, m, 64);
        uint32_t c1 = umin32(a1, b4), c2_ = umin32(a2, b3);
        uint32_t c3 = umin32(a3, b2), c4 = umin32(a4, b1);
        uint32_t lo, hi;
        lo = umin32(c1, c3); hi = umax32(c1, c3); c1 = lo; c3 = hi;
        lo = umin32(c2_, c4); hi = umax32(c2_, c4); c2_ = lo; c4 = hi;
        lo = umin32(c1, c2_); hi = umax32(c1, c2_); c1 = lo; c2_ = hi;
        lo = umin32(c3, c4); hi = umax32(c3, c4); c3 = lo; c4 = hi;
        a1 = c1; a2 = c2_; a3 = c3; a4 = c4;
      }
      if (fr == 0) {
        const int row = rowBase + i * 16 + fq * 4 + r;   // C/D layout (m89)
        part[(size_t)row * NSPLIT + blockIdx.y] = make_uint4(a1, a2, a3, a4);
      }
    }
}

// -------- merge: 64 candidates/row -> certain winner or fp64 rescore --------
__global__ __launch_bounds__(256) void vq_merge(const uint32_t* __restrict__ part,
                                                const float* __restrict__ x,
                                                const float* __restrict__ cb,
                                                float* __restrict__ out) {
  const int w = threadIdx.x >> 6, lane = threadIdx.x & 63;
  const int row = blockIdx.x * 4 + w;                 // one wave per row

  const uint32_t pk = part[(size_t)row * 64 + lane];  // coalesced, 1 cand/lane
  const int gidx = (lane >> 2) * (K_CB / NSPLIT) + (int)(pk & 511u);

  // integer min == numeric min (all packed values positive)
  uint32_t pmin = pk;
#pragma unroll
  for (int m = 1; m < 64; m <<= 1) {
    const uint32_t o = __shfl_xor(pmin, m, 64);
    pmin = pmin < o ? pmin : o;
  }
  const float vmin = __uint_as_float(pmin & ~511u);
  const float vme  = __uint_as_float(pk & ~511u);
  const unsigned long long mask = __ballot(vme <= vmin + EPS);

  int winner;
  if (__popcll(mask) == 1) {
    winner = __shfl(gidx, __ffsll((long long)mask) - 1, 64);
  } else {
    // exact fp64 rescore of the qualifiers (ties -> smaller index, like np)
    const f32x4 xv = *(const f32x4*)(x + (size_t)row * D_DIM + lane * 4);
    double bestd = 1.0e300;
    int bidx = 0x7fffffff;
    unsigned long long mm = mask;
    while (mm) {
      const int q = __ffsll((long long)mm) - 1;
      mm &= mm - 1;
      const int ci = __shfl(gidx, q, 64);
      const f32x4 cv = *(const f32x4*)(cb + (size_t)ci * D_DIM + lane * 4);
      double s = 0.0;
#pragma unroll
      for (int t = 0; t < 4; ++t) {
        const double dx = (double)xv[t] - (double)cv[t];
        s += dx * dx;
      }
#pragma unroll
      for (int m = 1; m < 64; m <<= 1) s += __shfl_xor(s, m, 64);
      if (s < bestd || (s == bestd && ci < bidx)) { bestd = s; bidx = ci; }
    }
    winner = bidx;
  }

  float* out_recon = out;                               // out_ze written by prep
  float* out_zq    = out + 2 * (size_t)M_ROWS * D_DIM;
  float* out_idx   = out + 3 * (size_t)M_ROWS * D_DIM;

  const f32x4 cv = *(const f32x4*)(cb + (size_t)winner * D_DIM + lane * 4);
  *(f32x4*)(out_recon + (size_t)row * D_DIM + lane * 4) = cv;  // identity decoder
  *(f32x4*)(out_zq    + (size_t)row * D_DIM + lane * 4) = cv;
  if (lane == 0) out_idx[row] = (float)winner;
}

extern "C" void kernel_launch(void* const* d_in, const int* in_sizes, int n_in,
                              void* d_out, int out_size, void* d_ws, size_t ws_size,
                              hipStream_t stream) {
  const float* x  = (const float*)d_in[0];
  const float* cb = (const float*)d_in[1];
  float* out = (float*)d_out;

  // ws: c2s 32 KB | part uint4[16384][16] 4 MB | Ap fp8 4 MB | Bp fp8 2 MB | pad
  char* ws = (char*)d_ws;
  float*    c2s  = (float*)ws;
  uint4*    part = (uint4*)(ws + 32768);
  uint8_t*  Ap   = (uint8_t*)(ws + 32768 + 4194304);
  uint8_t*  Bp   = Ap + (size_t)M_ROWS * D_DIM;
  if (ws_size < (size_t)(32768 + 4194304 + 4194304 + 2097152 + 4096)) return;

  float* out_ze = out + (size_t)M_ROWS * D_DIM;

  prep    <<<dim3(M_ROWS / 4 + K_CB / 4), dim3(256), 0, stream>>>(x, cb, Ap, Bp, c2s, out_ze);
  vq_main <<<dim3(M_ROWS / 128, NSPLIT), dim3(256), 0, stream>>>(Ap, Bp, c2s, part);
  vq_merge<<<dim3(M_ROWS / 4), dim3(256), 0, stream>>>((const uint32_t*)part, x, cb, out);
}

// Round 9
// 175.176 us; speedup vs baseline: 1.0121x; 1.0121x over previous
//
#include <hip/hip_runtime.h>
#include <stdint.h>

// VQ-VAE nearest-codeword quantization, MI355X (gfx950).
// M=16384 rows, D=256 dims, K=8192 codewords.
// argmin_k ||x-c_k||^2 == argmin_k ( ||c_k||^2 - 2 x.c_k )
//
// R16: R15 with the c2-preload spill removed. R15's cvv[8][4] (32 floats)
// half-spilled to scratch (WRITE_SIZE 4->36.7MB, VGPR pinned at 84) -- the
// latency fix worked (vq_main 66us, best recorded) but paid ~5us back in
// scratch BW. Now: 1-STAGE-AHEAD rotating c2 prefetch, 8 floats (cvc/cvn,
// static-indexed after full unroll -> registers). Loads for stage c+1 are
// issued at the SAME program point as R14 (right after stage c's barrier,
// no sync semantics change) but consumed a full stage (~600cy) later
// instead of ~10cy. Everything else identical to R15/R14:
// 2-buffer/__syncthreads skeleton, DMA a full stage ahead, XOR swizzle,
// shufflevector B-frag concat, med3 top-4 epilogue, serial-rescore merge.
// Refuted levers (counter evidence): no-LDS streaming (R9-R11), launch_bounds
// (256,4) (R12 spill), counted vmcnt+raw barrier (R13 HBM thrash),
// whole-split c2 preload (R15 partial spill).
// Numerics, proven absmax 0.0: forced-RTNE fp8, Ap=-2x with c2 pre-loaded in
// the MFMA C operand, TOP-4 per 512-col split, EPS=20 fp64 rescore,
// ties -> smaller index like np.argmin.

#define M_ROWS 16384
#define D_DIM  256
#define K_CB   8192
#define NSPLIT 16           // 512 codewords per split
#define CHUNK  64           // cols staged per barrier
#define EPS 20.0f

typedef float f32x4 __attribute__((ext_vector_type(4)));
typedef int   int4v __attribute__((ext_vector_type(4)));
typedef int   int8v __attribute__((ext_vector_type(8)));

__device__ __forceinline__ uint32_t umin32(uint32_t a, uint32_t b) { return a < b ? a : b; }
__device__ __forceinline__ uint32_t umax32(uint32_t a, uint32_t b) { return a > b ? a : b; }

// packed values are positive normal floats: float compare == uint compare
__device__ __forceinline__ uint32_t fmin32(uint32_t a, uint32_t b) {
  return __float_as_uint(fminf(__uint_as_float(a), __uint_as_float(b)));
}
__device__ __forceinline__ uint32_t fmed32(uint32_t a, uint32_t b, uint32_t c) {
  return __float_as_uint(__builtin_amdgcn_fmed3f(
      __uint_as_float(a), __uint_as_float(b), __uint_as_float(c)));
}

__device__ __forceinline__ void gld_lds16(const void* g, void* l) {
  // async global->LDS, 16B/lane; LDS dest is wave-uniform base + lane*16.
  __builtin_amdgcn_global_load_lds((__attribute__((address_space(1))) void*)g,
                                   (__attribute__((address_space(3))) void*)l,
                                   16, 0, 0);
}

// round f32 to 3 mantissa bits, RTNE (carry into exponent handled by the add)
__device__ __forceinline__ float rtne3(float f) {
  uint32_t u = __float_as_uint(f);
  u = (u + 0x0007FFFFu + ((u >> 20) & 1u)) & 0xFFF00000u;
  return __uint_as_float(u);
}

__device__ __forceinline__ uint32_t fp8x4(const f32x4 v) {
  // pre-rounded values are exactly representable -> intrinsic is exact
  int p = __builtin_amdgcn_cvt_pk_fp8_f32(rtne3(v[0]), rtne3(v[1]), 0, false);
  p = __builtin_amdgcn_cvt_pk_fp8_f32(rtne3(v[2]), rtne3(v[3]), p, true);
  return (uint32_t)p;
}

// -- prep: x -> Ap fp8(-2x) + out_ze ; cb -> Bp fp8 + c2s = ||c||^2+1024 ----
__global__ __launch_bounds__(256) void prep(const float* __restrict__ x,
                                            const float* __restrict__ cb,
                                            uint8_t* __restrict__ Ap,
                                            uint8_t* __restrict__ Bp,
                                            float* __restrict__ c2s,
                                            float* __restrict__ out_ze) {
  const int w = threadIdx.x >> 6, lane = threadIdx.x & 63;
  if (blockIdx.x < M_ROWS / 4) {
    const int row = blockIdx.x * 4 + w;                 // one wave per x row
    const f32x4 v = *(const f32x4*)(x + (size_t)row * D_DIM + lane * 4);
    // store -2x: exact (sign+exponent), q(-2x)q(c) == -2 q(x)q(c) bit-exact,
    // so the EPS error bound is unchanged. |2x| <= ~11 << 448 (e4m3 max).
    f32x4 nv;
#pragma unroll
    for (int t = 0; t < 4; ++t) nv[t] = -2.0f * v[t];
    *(uint32_t*)(Ap + (size_t)row * D_DIM + lane * 4) = fp8x4(nv);
    *(f32x4*)(out_ze + (size_t)row * D_DIM + lane * 4) = v;   // identity encoder
  } else {
    const int row = (blockIdx.x - M_ROWS / 4) * 4 + w;  // one wave per codeword
    const f32x4 v = *(const f32x4*)(cb + (size_t)row * D_DIM + lane * 4);
    *(uint32_t*)(Bp + (size_t)row * D_DIM + lane * 4) = fp8x4(v);
    double s = 0.0;
#pragma unroll
    for (int t = 0; t < 4; ++t) s += (double)v[t] * (double)v[t];
#pragma unroll
    for (int m = 1; m < 64; m <<= 1) s += __shfl_xor(s, m, 64);
    if (lane == 0) c2s[row] = (float)s + 1024.0f;       // pre-shifted: s>0 packing
  }
}

// ---- main: fp8 K=256 GEMM, DMA-pipelined LDS B, fused packed top-4/split ----
__global__ __launch_bounds__(256, 3) void vq_main(const uint8_t* __restrict__ Ap,
                                                  const uint8_t* __restrict__ Bp,
                                                  const float* __restrict__ c2s,
                                                  uint4* __restrict__ part) {
  __shared__ uint8_t Bs[2][CHUNK * D_DIM];   // 2 x 16 KB, chunk-swizzled

  const int w    = threadIdx.x >> 6;
  const int lane = threadIdx.x & 63;
  const int fr   = lane & 15;         // frag m/n index
  const int fq   = lane >> 4;         // frag k-quarter (32 contiguous bytes)

  const int rowBase = blockIdx.x * 128 + w * 32;        // wave owns 32 rows
  const int colBase = blockIdx.y * 512;                 // block owns one split

  // A fragments (-2x) for the whole kernel
  int8v af[2][2];
  {
    const uint8_t* ab = Ap + (size_t)(rowBase + fr) * D_DIM + fq * 32;
#pragma unroll
    for (int i = 0; i < 2; ++i)
#pragma unroll
      for (int kh = 0; kh < 2; ++kh)
        af[i][kh] = *(const int8v*)(ab + (size_t)(i * 16) * D_DIM + kh * 128);
  }

  // stage-invariant DMA offsets: row rr = ii*4+dRow within the wave's 16 rows;
  // phys 16B chunk p of row n holds logical chunk p^(n&15), applied on the
  // GLOBAL source address (gld dest is wave-uniform base + lane*16).
  const int dRow = lane >> 4;
  const int dChk = lane & 15;
  int goff[4];
#pragma unroll
  for (int ii = 0; ii < 4; ++ii) {
    const int rr = ii * 4 + dRow;                       // == row & 15
    goff[ii] = rr * D_DIM + ((dChk ^ rr) << 4);
  }

#define STAGE_DMA(c, buf)                                                      \
  {                                                                            \
    const uint8_t* gb = Bp + ((size_t)(colBase + (c) * CHUNK + w * 16) << 8);  \
    uint8_t* lb = &Bs[buf][w * 16 * D_DIM] + lane * 16;                        \
    _Pragma("unroll")                                                          \
    for (int ii = 0; ii < 4; ++ii)                                             \
      gld_lds16(gb + goff[ii], lb + ii * 4 * D_DIM);                           \
  }

  // sorted top-4 per slot [i][r], packed ((s+1024) bits & ~511) | col9
  uint32_t t1[2][4], t2[2][4], t3[2][4], t4[2][4];
#pragma unroll
  for (int i = 0; i < 2; ++i)
#pragma unroll
    for (int r = 0; r < 4; ++r) {
      t1[i][r] = 0x7f7ffe00u; t2[i][r] = 0x7f7ffe00u;
      t3[i][r] = 0x7f7ffe00u; t4[i][r] = 0x7f7ffe00u;
    }

  // 1-stage-ahead rotating c2 prefetch: cvc = stage c (consumed now),
  // cvn = stage c+1 (issued now, consumed next stage, ~600cy away).
  // 8 floats, static-indexed after full unroll -> registers (no R15 spill).
  const float* c2p = c2s + colBase + fr;
  float cvc[4], cvn[4];
#pragma unroll
  for (int jj = 0; jj < 4; ++jj) cvc[jj] = c2p[jj * 16];

  const int y0 = (fq * 2) << 4;                         // logical 32B k-quarter

  STAGE_DMA(0, 0);

#pragma unroll
  for (int c = 0; c < 512 / CHUNK; ++c) {               // 8 stages, unrolled
    __syncthreads();              // DMA[c] landed (issued a full stage ago)
    if (c < 512 / CHUNK - 1) {
      STAGE_DMA(c + 1, (c + 1) & 1);
#pragma unroll
      for (int jj = 0; jj < 4; ++jj)                    // prefetch next c2
        cvn[jj] = c2p[(c + 1) * CHUNK + jj * 16];
    }

    const uint8_t* bsb = Bs[c & 1];
    const int cb0 = c * CHUNK;

#pragma unroll
    for (int jj = 0; jj < 4; ++jj) {                    // 4 col-frags of 16
      const uint8_t* bp = bsb + (jj * 16 + fr) * D_DIM;
      const float cv = cvc[jj];
      f32x4 acc[2];
      acc[0] = (f32x4){cv, cv, cv, cv};                 // c2 pre-loaded into C
      acc[1] = (f32x4){cv, cv, cv, cv};
#pragma unroll
      for (int kh = 0; kh < 2; ++kh) {
        const int y = (y0 ^ (fr << 4)) ^ (kh << 7);     // ((L0^fr)<<4)
        const int4v lo = *(const int4v*)(bp + y);
        const int4v hi = *(const int4v*)(bp + (y ^ 16));
        const int8v bf = __builtin_shufflevector(lo, hi, 0, 1, 2, 3, 4, 5, 6, 7);
#pragma unroll
        for (int i = 0; i < 2; ++i)
          acc[i] = __builtin_amdgcn_mfma_scale_f32_16x16x128_f8f6f4(
              af[i][kh], bf, acc[i], 0, 0,       // cbsz=fp8, blgp=fp8
              0, 0x7f7f7f7f, 0, 0x7f7f7f7f);     // unit E8M0 scales
      }
      // epilogue: acc == s = (1024+c2) - 2*cross; pack; med3 top-4 insert
      const int col9 = cb0 + jj * 16 + fr;
#pragma unroll
      for (int i = 0; i < 2; ++i)
#pragma unroll
        for (int r = 0; r < 4; ++r) {
          const uint32_t p =
              (__float_as_uint(acc[i][r]) & ~511u) | (uint32_t)col9;
          const uint32_t o1 = t1[i][r], o2 = t2[i][r];
          const uint32_t o3 = t3[i][r], o4 = t4[i][r];
          t1[i][r] = fmin32(p, o1);                 // 4 independent ops,
          t2[i][r] = fmed32(p, o1, o2);             // no serial chain
          t3[i][r] = fmed32(p, o2, o3);
          t4[i][r] = fmed32(p, o3, o4);
        }
    }

#pragma unroll
    for (int jj = 0; jj < 4; ++jj) cvc[jj] = cvn[jj];   // rotate (4 v_mov)
  }

  // cross-fr bitonic merge (lanes with same fq hold the same rows, disjoint
  // cols); lane fr==0 of each fq then stores its rows' top-4 directly.
#pragma unroll
  for (int i = 0; i < 2; ++i)
#pragma unroll
    for (int r = 0; r < 4; ++r) {
      uint32_t a1 = t1[i][r], a2 = t2[i][r], a3 = t3[i][r], a4 = t4[i][r];
#pragma unroll
      for (int m = 1; m < 16; m <<= 1) {
        const uint32_t b1 = __shfl_xor(a1, m, 64);
        const uint32_t b2 = __shfl_xor(a2, m, 64);
        const uint32_t b3 = __shfl_xor(a3, m, 64);
        const uint32_t b4 = __shfl_xor(a4, m, 64);
        uint32_t c1 = umin32(a1, b4), c2_ = umin32(a2, b3);
        uint32_t c3 = umin32(a3, b2), c4 = umin32(a4, b1);
        uint32_t lo, hi;
        lo = umin32(c1, c3); hi = umax32(c1, c3); c1 = lo; c3 = hi;
        lo = umin32(c2_, c4); hi = umax32(c2_, c4); c2_ = lo; c4 = hi;
        lo = umin32(c1, c2_); hi = umax32(c1, c2_); c1 = lo; c2_ = hi;
        lo = umin32(c3, c4); hi = umax32(c3, c4); c3 = lo; c4 = hi;
        a1 = c1; a2 = c2_; a3 = c3; a4 = c4;
      }
      if (fr == 0) {
        const int row = rowBase + i * 16 + fq * 4 + r;   // C/D layout (m89)
        part[(size_t)row * NSPLIT + blockIdx.y] = make_uint4(a1, a2, a3, a4);
      }
    }
}

// -------- merge: 64 candidates/row -> certain winner or fp64 rescore --------
__global__ __launch_bounds__(256) void vq_merge(const uint32_t* __restrict__ part,
                                                const float* __restrict__ x,
                                                const float* __restrict__ cb,
                                                float* __restrict__ out) {
  const int w = threadIdx.x >> 6, lane = threadIdx.x & 63;
  const int row = blockIdx.x * 4 + w;                 // one wave per row

  const uint32_t pk = part[(size_t)row * 64 + lane];  // coalesced, 1 cand/lane
  const int gidx = (lane >> 2) * (K_CB / NSPLIT) + (int)(pk & 511u);

  // integer min == numeric min (all packed values positive)
  uint32_t pmin = pk;
#pragma unroll
  for (int m = 1; m < 64; m <<= 1) {
    const uint32_t o = __shfl_xor(pmin, m, 64);
    pmin = pmin < o ? pmin : o;
  }
  const float vmin = __uint_as_float(pmin & ~511u);
  const float vme  = __uint_as_float(pk & ~511u);
  const unsigned long long mask = __ballot(vme <= vmin + EPS);

  int winner;
  if (__popcll(mask) == 1) {
    winner = __shfl(gidx, __ffsll((long long)mask) - 1, 64);
  } else {
    // exact fp64 rescore of the qualifiers (ties -> smaller index, like np)
    const f32x4 xv = *(const f32x4*)(x + (size_t)row * D_DIM + lane * 4);
    double bestd = 1.0e300;
    int bidx = 0x7fffffff;
    unsigned long long mm = mask;
    while (mm) {
      const int q = __ffsll((long long)mm) - 1;
      mm &= mm - 1;
      const int ci = __shfl(gidx, q, 64);
      const f32x4 cv = *(const f32x4*)(cb + (size_t)ci * D_DIM + lane * 4);
      double s = 0.0;
#pragma unroll
      for (int t = 0; t < 4; ++t) {
        const double dx = (double)xv[t] - (double)cv[t];
        s += dx * dx;
      }
#pragma unroll
      for (int m = 1; m < 64; m <<= 1) s += __shfl_xor(s, m, 64);
      if (s < bestd || (s == bestd && ci < bidx)) { bestd = s; bidx = ci; }
    }
    winner = bidx;
  }

  float* out_recon = out;                               // out_ze written by prep
  float* out_zq    = out + 2 * (size_t)M_ROWS * D_DIM;
  float* out_idx   = out + 3 * (size_t)M_ROWS * D_DIM;

  const f32x4 cv = *(const f32x4*)(cb + (size_t)winner * D_DIM + lane * 4);
  *(f32x4*)(out_recon + (size_t)row * D_DIM + lane * 4) = cv;  // identity decoder
  *(f32x4*)(out_zq    + (size_t)row * D_DIM + lane * 4) = cv;
  if (lane == 0) out_idx[row] = (float)winner;
}

extern "C" void kernel_launch(void* const* d_in, const int* in_sizes, int n_in,
                              void* d_out, int out_size, void* d_ws, size_t ws_size,
                              hipStream_t stream) {
  const float* x  = (const float*)d_in[0];
  const float* cb = (const float*)d_in[1];
  float* out = (float*)d_out;

  // ws: c2s 32 KB | part uint4[16384][16] 4 MB | Ap fp8 4 MB | Bp fp8 2 MB | pad
  char* ws = (char*)d_ws;
  float*    c2s  = (float*)ws;
  uint4*    part = (uint4*)(ws + 32768);
  uint8_t*  Ap   = (uint8_t*)(ws + 32768 + 4194304);
  uint8_t*  Bp   = Ap + (size_t)M_ROWS * D_DIM;
  if (ws_size < (size_t)(32768 + 4194304 + 4194304 + 2097152 + 4096)) return;

  float* out_ze = out + (size_t)M_ROWS * D_DIM;

  prep    <<<dim3(M_ROWS / 4 + K_CB / 4), dim3(256), 0, stream>>>(x, cb, Ap, Bp, c2s, out_ze);
  vq_main <<<dim3(M_ROWS / 128, NSPLIT), dim3(256), 0, stream>>>(Ap, Bp, c2s, part);
  vq_merge<<<dim3(M_ROWS / 4), dim3(256), 0, stream>>>((const uint32_t*)part, x, cb, out);
}

// Round 10
// 172.298 us; speedup vs baseline: 1.0290x; 1.0167x over previous
//
#include <hip/hip_runtime.h>
#include <stdint.h>

// VQ-VAE nearest-codeword quantization, MI355X (gfx950).
// M=16384 rows, D=256 dims, K=8192 codewords.
// argmin_k ||x-c_k||^2 == argmin_k ( ||c_k||^2 - 2 x.c_k )
//
// R17: spill isolated to the FULL UNROLL of the 8-stage loop (R14 rolled =
// WRITE 4MB clean; R15/R16 unrolled = ~30MB scratch at VGPR=84, ~half the
// c2-prefetch gain given back). This round: outer stage loop ROLLED (R14
// form), keeping the two proven wins:
//  - 1-stage-ahead rotating c2 prefetch (cvc/cvn, static inner indices ->
//    registers in a rolled loop): c2 loads issued right after the barrier,
//    consumed a full stage (~600cy) later, not ~10cy.
//  - shufflevector B-frag concat (elides up to 16 v_mov per col-group).
// Skeleton unchanged (R13 proved sync grafts regress): 2 LDS buffers,
// __syncthreads per stage, DMA a full stage ahead, 16-chunk XOR swizzle.
// merge: serial-rescore. prep unchanged.
// Refuted levers (counter evidence): no-LDS streaming (R9-R11), launch_bounds
// (256,4) (R12 spill), counted vmcnt+raw barrier (R13 HBM thrash), 8-stage
// full unroll (R15/R16 scratch spill).
// Numerics, proven absmax 0.0: forced-RTNE fp8, Ap=-2x with c2 pre-loaded in
// the MFMA C operand, med3 sorted top-4 per 512-col split, EPS=20 fp64
// rescore, ties -> smaller index like np.argmin.

#define M_ROWS 16384
#define D_DIM  256
#define K_CB   8192
#define NSPLIT 16           // 512 codewords per split
#define CHUNK  64           // cols staged per barrier
#define EPS 20.0f

typedef float f32x4 __attribute__((ext_vector_type(4)));
typedef int   int4v __attribute__((ext_vector_type(4)));
typedef int   int8v __attribute__((ext_vector_type(8)));

__device__ __forceinline__ uint32_t umin32(uint32_t a, uint32_t b) { return a < b ? a : b; }
__device__ __forceinline__ uint32_t umax32(uint32_t a, uint32_t b) { return a > b ? a : b; }

// packed values are positive normal floats: float compare == uint compare
__device__ __forceinline__ uint32_t fmin32(uint32_t a, uint32_t b) {
  return __float_as_uint(fminf(__uint_as_float(a), __uint_as_float(b)));
}
__device__ __forceinline__ uint32_t fmed32(uint32_t a, uint32_t b, uint32_t c) {
  return __float_as_uint(__builtin_amdgcn_fmed3f(
      __uint_as_float(a), __uint_as_float(b), __uint_as_float(c)));
}

__device__ __forceinline__ void gld_lds16(const void* g, void* l) {
  // async global->LDS, 16B/lane; LDS dest is wave-uniform base + lane*16.
  __builtin_amdgcn_global_load_lds((__attribute__((address_space(1))) void*)g,
                                   (__attribute__((address_space(3))) void*)l,
                                   16, 0, 0);
}

// round f32 to 3 mantissa bits, RTNE (carry into exponent handled by the add)
__device__ __forceinline__ float rtne3(float f) {
  uint32_t u = __float_as_uint(f);
  u = (u + 0x0007FFFFu + ((u >> 20) & 1u)) & 0xFFF00000u;
  return __uint_as_float(u);
}

__device__ __forceinline__ uint32_t fp8x4(const f32x4 v) {
  // pre-rounded values are exactly representable -> intrinsic is exact
  int p = __builtin_amdgcn_cvt_pk_fp8_f32(rtne3(v[0]), rtne3(v[1]), 0, false);
  p = __builtin_amdgcn_cvt_pk_fp8_f32(rtne3(v[2]), rtne3(v[3]), p, true);
  return (uint32_t)p;
}

// -- prep: x -> Ap fp8(-2x) + out_ze ; cb -> Bp fp8 + c2s = ||c||^2+1024 ----
__global__ __launch_bounds__(256) void prep(const float* __restrict__ x,
                                            const float* __restrict__ cb,
                                            uint8_t* __restrict__ Ap,
                                            uint8_t* __restrict__ Bp,
                                            float* __restrict__ c2s,
                                            float* __restrict__ out_ze) {
  const int w = threadIdx.x >> 6, lane = threadIdx.x & 63;
  if (blockIdx.x < M_ROWS / 4) {
    const int row = blockIdx.x * 4 + w;                 // one wave per x row
    const f32x4 v = *(const f32x4*)(x + (size_t)row * D_DIM + lane * 4);
    // store -2x: exact (sign+exponent), q(-2x)q(c) == -2 q(x)q(c) bit-exact,
    // so the EPS error bound is unchanged. |2x| <= ~11 << 448 (e4m3 max).
    f32x4 nv;
#pragma unroll
    for (int t = 0; t < 4; ++t) nv[t] = -2.0f * v[t];
    *(uint32_t*)(Ap + (size_t)row * D_DIM + lane * 4) = fp8x4(nv);
    *(f32x4*)(out_ze + (size_t)row * D_DIM + lane * 4) = v;   // identity encoder
  } else {
    const int row = (blockIdx.x - M_ROWS / 4) * 4 + w;  // one wave per codeword
    const f32x4 v = *(const f32x4*)(cb + (size_t)row * D_DIM + lane * 4);
    *(uint32_t*)(Bp + (size_t)row * D_DIM + lane * 4) = fp8x4(v);
    double s = 0.0;
#pragma unroll
    for (int t = 0; t < 4; ++t) s += (double)v[t] * (double)v[t];
#pragma unroll
    for (int m = 1; m < 64; m <<= 1) s += __shfl_xor(s, m, 64);
    if (lane == 0) c2s[row] = (float)s + 1024.0f;       // pre-shifted: s>0 packing
  }
}

// ---- main: fp8 K=256 GEMM, DMA-pipelined LDS B, fused packed top-4/split ----
__global__ __launch_bounds__(256, 3) void vq_main(const uint8_t* __restrict__ Ap,
                                                  const uint8_t* __restrict__ Bp,
                                                  const float* __restrict__ c2s,
                                                  uint4* __restrict__ part) {
  __shared__ uint8_t Bs[2][CHUNK * D_DIM];   // 2 x 16 KB, chunk-swizzled

  const int w    = threadIdx.x >> 6;
  const int lane = threadIdx.x & 63;
  const int fr   = lane & 15;         // frag m/n index
  const int fq   = lane >> 4;         // frag k-quarter (32 contiguous bytes)

  const int rowBase = blockIdx.x * 128 + w * 32;        // wave owns 32 rows
  const int colBase = blockIdx.y * 512;                 // block owns one split

  // A fragments (-2x) for the whole kernel
  int8v af[2][2];
  {
    const uint8_t* ab = Ap + (size_t)(rowBase + fr) * D_DIM + fq * 32;
#pragma unroll
    for (int i = 0; i < 2; ++i)
#pragma unroll
      for (int kh = 0; kh < 2; ++kh)
        af[i][kh] = *(const int8v*)(ab + (size_t)(i * 16) * D_DIM + kh * 128);
  }

  // stage-invariant DMA offsets: row rr = ii*4+dRow within the wave's 16 rows;
  // phys 16B chunk p of row n holds logical chunk p^(n&15), applied on the
  // GLOBAL source address (gld dest is wave-uniform base + lane*16).
  const int dRow = lane >> 4;
  const int dChk = lane & 15;
  int goff[4];
#pragma unroll
  for (int ii = 0; ii < 4; ++ii) {
    const int rr = ii * 4 + dRow;                       // == row & 15
    goff[ii] = rr * D_DIM + ((dChk ^ rr) << 4);
  }

#define STAGE_DMA(c, buf)                                                      \
  {                                                                            \
    const uint8_t* gb = Bp + ((size_t)(colBase + (c) * CHUNK + w * 16) << 8);  \
    uint8_t* lb = &Bs[buf][w * 16 * D_DIM] + lane * 16;                        \
    _Pragma("unroll")                                                          \
    for (int ii = 0; ii < 4; ++ii)                                             \
      gld_lds16(gb + goff[ii], lb + ii * 4 * D_DIM);                           \
  }

  // sorted top-4 per slot [i][r], packed ((s+1024) bits & ~511) | col9
  uint32_t t1[2][4], t2[2][4], t3[2][4], t4[2][4];
#pragma unroll
  for (int i = 0; i < 2; ++i)
#pragma unroll
    for (int r = 0; r < 4; ++r) {
      t1[i][r] = 0x7f7ffe00u; t2[i][r] = 0x7f7ffe00u;
      t3[i][r] = 0x7f7ffe00u; t4[i][r] = 0x7f7ffe00u;
    }

  // 1-stage-ahead rotating c2 prefetch: cvc = stage c (consumed now),
  // cvn = stage c+1 (issued right after the barrier, consumed ~600cy later).
  // Static inner indices -> registers; outer loop stays ROLLED (no spill).
  const float* c2p = c2s + colBase + fr;
  float cvc[4], cvn[4];
#pragma unroll
  for (int jj = 0; jj < 4; ++jj) cvc[jj] = c2p[jj * 16];

  const int y0 = (fq * 2) << 4;                         // logical 32B k-quarter

  STAGE_DMA(0, 0);

  for (int c = 0; c < 512 / CHUNK; ++c) {               // 8 stages, rolled
    __syncthreads();              // DMA[c] landed (issued a full stage ago)
    if (c < 512 / CHUNK - 1) {
      STAGE_DMA(c + 1, (c + 1) & 1);
#pragma unroll
      for (int jj = 0; jj < 4; ++jj)                    // prefetch next c2
        cvn[jj] = c2p[(c + 1) * CHUNK + jj * 16];
    }

    const uint8_t* bsb = Bs[c & 1];
    const int cb0 = c * CHUNK;

#pragma unroll
    for (int jj = 0; jj < 4; ++jj) {                    // 4 col-frags of 16
      const uint8_t* bp = bsb + (jj * 16 + fr) * D_DIM;
      const float cv = cvc[jj];
      f32x4 acc[2];
      acc[0] = (f32x4){cv, cv, cv, cv};                 // c2 pre-loaded into C
      acc[1] = (f32x4){cv, cv, cv, cv};
#pragma unroll
      for (int kh = 0; kh < 2; ++kh) {
        const int y = (y0 ^ (fr << 4)) ^ (kh << 7);     // ((L0^fr)<<4)
        const int4v lo = *(const int4v*)(bp + y);
        const int4v hi = *(const int4v*)(bp + (y ^ 16));
        const int8v bf = __builtin_shufflevector(lo, hi, 0, 1, 2, 3, 4, 5, 6, 7);
#pragma unroll
        for (int i = 0; i < 2; ++i)
          acc[i] = __builtin_amdgcn_mfma_scale_f32_16x16x128_f8f6f4(
              af[i][kh], bf, acc[i], 0, 0,       // cbsz=fp8, blgp=fp8
              0, 0x7f7f7f7f, 0, 0x7f7f7f7f);     // unit E8M0 scales
      }
      // epilogue: acc == s = (1024+c2) - 2*cross; pack; med3 top-4 insert
      const int col9 = cb0 + jj * 16 + fr;
#pragma unroll
      for (int i = 0; i < 2; ++i)
#pragma unroll
        for (int r = 0; r < 4; ++r) {
          const uint32_t p =
              (__float_as_uint(acc[i][r]) & ~511u) | (uint32_t)col9;
          const uint32_t o1 = t1[i][r], o2 = t2[i][r];
          const uint32_t o3 = t3[i][r], o4 = t4[i][r];
          t1[i][r] = fmin32(p, o1);                 // 4 independent ops,
          t2[i][r] = fmed32(p, o1, o2);             // no serial chain
          t3[i][r] = fmed32(p, o2, o3);
          t4[i][r] = fmed32(p, o3, o4);
        }
    }

    if (c < 512 / CHUNK - 1) {
#pragma unroll
      for (int jj = 0; jj < 4; ++jj) cvc[jj] = cvn[jj]; // rotate (4 v_mov)
    }
  }

  // cross-fr bitonic merge (lanes with same fq hold the same rows, disjoint
  // cols); lane fr==0 of each fq then stores its rows' top-4 directly.
#pragma unroll
  for (int i = 0; i < 2; ++i)
#pragma unroll
    for (int r = 0; r < 4; ++r) {
      uint32_t a1 = t1[i][r], a2 = t2[i][r], a3 = t3[i][r], a4 = t4[i][r];
#pragma unroll
      for (int m = 1; m < 16; m <<= 1) {
        const uint32_t b1 = __shfl_xor(a1, m, 64);
        const uint32_t b2 = __shfl_xor(a2, m, 64);
        const uint32_t b3 = __shfl_xor(a3, m, 64);
        const uint32_t b4 = __shfl_xor(a4, m, 64);
        uint32_t c1 = umin32(a1, b4), c2_ = umin32(a2, b3);
        uint32_t c3 = umin32(a3, b2), c4 = umin32(a4, b1);
        uint32_t lo, hi;
        lo = umin32(c1, c3); hi = umax32(c1, c3); c1 = lo; c3 = hi;
        lo = umin32(c2_, c4); hi = umax32(c2_, c4); c2_ = lo; c4 = hi;
        lo = umin32(c1, c2_); hi = umax32(c1, c2_); c1 = lo; c2_ = hi;
        lo = umin32(c3, c4); hi = umax32(c3, c4); c3 = lo; c4 = hi;
        a1 = c1; a2 = c2_; a3 = c3; a4 = c4;
      }
      if (fr == 0) {
        const int row = rowBase + i * 16 + fq * 4 + r;   // C/D layout (m89)
        part[(size_t)row * NSPLIT + blockIdx.y] = make_uint4(a1, a2, a3, a4);
      }
    }
}

// -------- merge: 64 candidates/row -> certain winner or fp64 rescore --------
__global__ __launch_bounds__(256) void vq_merge(const uint32_t* __restrict__ part,
                                                const float* __restrict__ x,
                                                const float* __restrict__ cb,
                                                float* __restrict__ out) {
  const int w = threadIdx.x >> 6, lane = threadIdx.x & 63;
  const int row = blockIdx.x * 4 + w;                 // one wave per row

  const uint32_t pk = part[(size_t)row * 64 + lane];  // coalesced, 1 cand/lane
  const int gidx = (lane >> 2) * (K_CB / NSPLIT) + (int)(pk & 511u);

  // integer min == numeric min (all packed values positive)
  uint32_t pmin = pk;
#pragma unroll
  for (int m = 1; m < 64; m <<= 1) {
    const uint32_t o = __shfl_xor(pmin, m, 64);
    pmin = pmin < o ? pmin : o;
  }
  const float vmin = __uint_as_float(pmin & ~511u);
  const float vme  = __uint_as_float(pk & ~511u);
  const unsigned long long mask = __ballot(vme <= vmin + EPS);

  int winner;
  if (__popcll(mask) == 1) {
    winner = __shfl(gidx, __ffsll((long long)mask) - 1, 64);
  } else {
    // exact fp64 rescore of the qualifiers (ties -> smaller index, like np)
    const f32x4 xv = *(const f32x4*)(x + (size_t)row * D_DIM + lane * 4);
    double bestd = 1.0e300;
    int bidx = 0x7fffffff;
    unsigned long long mm = mask;
    while (mm) {
      const int q = __ffsll((long long)mm) - 1;
      mm &= mm - 1;
      const int ci = __shfl(gidx, q, 64);
      const f32x4 cv = *(const f32x4*)(cb + (size_t)ci * D_DIM + lane * 4);
      double s = 0.0;
#pragma unroll
      for (int t = 0; t < 4; ++t) {
        const double dx = (double)xv[t] - (double)cv[t];
        s += dx * dx;
      }
#pragma unroll
      for (int m = 1; m < 64; m <<= 1) s += __shfl_xor(s, m, 64);
      if (s < bestd || (s == bestd && ci < bidx)) { bestd = s; bidx = ci; }
    }
    winner = bidx;
  }

  float* out_recon = out;                               // out_ze written by prep
  float* out_zq    = out + 2 * (size_t)M_ROWS * D_DIM;
  float* out_idx   = out + 3 * (size_t)M_ROWS * D_DIM;

  const f32x4 cv = *(const f32x4*)(cb + (size_t)winner * D_DIM + lane * 4);
  *(f32x4*)(out_recon + (size_t)row * D_DIM + lane * 4) = cv;  // identity decoder
  *(f32x4*)(out_zq    + (size_t)row * D_DIM + lane * 4) = cv;
  if (lane == 0) out_idx[row] = (float)winner;
}

extern "C" void kernel_launch(void* const* d_in, const int* in_sizes, int n_in,
                              void* d_out, int out_size, void* d_ws, size_t ws_size,
                              hipStream_t stream) {
  const float* x  = (const float*)d_in[0];
  const float* cb = (const float*)d_in[1];
  float* out = (float*)d_out;

  // ws: c2s 32 KB | part uint4[16384][16] 4 MB | Ap fp8 4 MB | Bp fp8 2 MB | pad
  char* ws = (char*)d_ws;
  float*    c2s  = (float*)ws;
  uint4*    part = (uint4*)(ws + 32768);
  uint8_t*  Ap   = (uint8_t*)(ws + 32768 + 4194304);
  uint8_t*  Bp   = Ap + (size_t)M_ROWS * D_DIM;
  if (ws_size < (size_t)(32768 + 4194304 + 4194304 + 2097152 + 4096)) return;

  float* out_ze = out + (size_t)M_ROWS * D_DIM;

  prep    <<<dim3(M_ROWS / 4 + K_CB / 4), dim3(256), 0, stream>>>(x, cb, Ap, Bp, c2s, out_ze);
  vq_main <<<dim3(M_ROWS / 128, NSPLIT), dim3(256), 0, stream>>>(Ap, Bp, c2s, part);
  vq_merge<<<dim3(M_ROWS / 4), dim3(256), 0, stream>>>((const uint32_t*)part, x, cb, out);
}

// Round 11
// 171.079 us; speedup vs baseline: 1.0363x; 1.0071x over previous
//
#include <hip/hip_runtime.h>
#include <stdint.h>

// VQ-VAE nearest-codeword quantization, MI355X (gfx950).
// M=16384 rows, D=256 dims, K=8192 codewords.
// argmin_k ||x-c_k||^2 == argmin_k ( ||c_k||^2 - 2 x.c_k )
//
// R18: R17 (172.3us total, vq_main 63.3us, all counters clean) + VALU
// addressing diet. R17 counters: MfmaUtil 22 + VALUBusy 61 = ~83% combined
// issue occupancy -> VALU instruction COUNT is the limiter. Two cuts, sync
// skeleton byte-identical (R13 proved sync grafts regress):
//  1. Immediate-offset LDS reads: every per-stage ds_read address is
//     base(c&1) + aK + jj*4096 with aK per-lane loop-invariant
//     (a0 = fr*256 + (y0^(fr<<4)), a1=a0^16, a2=a0^128, a3=a0^144; the XORs
//     stay within the low byte so they never carry into fr*256). jj*4096
//     folds into the 16-bit ds offset immediate -> address VALU per stage
//     drops from ~32 to ~4.
//  2. Shared MFMA C-operand: cvv4 built once per jj, used as the read-only
//     C input of BOTH i-chains' first MFMA (t=mfma(af[i][0],bf0,cvv4);
//     acc=mfma(af[i][1],bf1,t)) -> acc-init movs halved (8->4 per jj).
// Kept from R17: rolled 8-stage loop (unroll spills, R15/R16), 1-stage-ahead
// c2 prefetch, shufflevector B-frag concat, 2-buffer/__syncthreads skeleton,
// DMA a full stage ahead, 16-chunk XOR swizzle, serial-rescore merge.
// Refuted levers (counter evidence): no-LDS streaming (R9-R11), launch_bounds
// (256,4) (R12 spill), counted vmcnt+raw barrier (R13 HBM thrash), 8-stage
// full unroll (R15/R16 scratch spill).
// Numerics, proven absmax 0.0: forced-RTNE fp8, Ap=-2x with c2 pre-loaded in
// the MFMA C operand, med3 sorted top-4 per 512-col split, EPS=20 fp64
// rescore, ties -> smaller index like np.argmin.

#define M_ROWS 16384
#define D_DIM  256
#define K_CB   8192
#define NSPLIT 16           // 512 codewords per split
#define CHUNK  64           // cols staged per barrier
#define EPS 20.0f

typedef float f32x4 __attribute__((ext_vector_type(4)));
typedef int   int4v __attribute__((ext_vector_type(4)));
typedef int   int8v __attribute__((ext_vector_type(8)));

__device__ __forceinline__ uint32_t umin32(uint32_t a, uint32_t b) { return a < b ? a : b; }
__device__ __forceinline__ uint32_t umax32(uint32_t a, uint32_t b) { return a > b ? a : b; }

// packed values are positive normal floats: float compare == uint compare
__device__ __forceinline__ uint32_t fmin32(uint32_t a, uint32_t b) {
  return __float_as_uint(fminf(__uint_as_float(a), __uint_as_float(b)));
}
__device__ __forceinline__ uint32_t fmed32(uint32_t a, uint32_t b, uint32_t c) {
  return __float_as_uint(__builtin_amdgcn_fmed3f(
      __uint_as_float(a), __uint_as_float(b), __uint_as_float(c)));
}

__device__ __forceinline__ void gld_lds16(const void* g, void* l) {
  // async global->LDS, 16B/lane; LDS dest is wave-uniform base + lane*16.
  __builtin_amdgcn_global_load_lds((__attribute__((address_space(1))) void*)g,
                                   (__attribute__((address_space(3))) void*)l,
                                   16, 0, 0);
}

// round f32 to 3 mantissa bits, RTNE (carry into exponent handled by the add)
__device__ __forceinline__ float rtne3(float f) {
  uint32_t u = __float_as_uint(f);
  u = (u + 0x0007FFFFu + ((u >> 20) & 1u)) & 0xFFF00000u;
  return __uint_as_float(u);
}

__device__ __forceinline__ uint32_t fp8x4(const f32x4 v) {
  // pre-rounded values are exactly representable -> intrinsic is exact
  int p = __builtin_amdgcn_cvt_pk_fp8_f32(rtne3(v[0]), rtne3(v[1]), 0, false);
  p = __builtin_amdgcn_cvt_pk_fp8_f32(rtne3(v[2]), rtne3(v[3]), p, true);
  return (uint32_t)p;
}

// -- prep: x -> Ap fp8(-2x) + out_ze ; cb -> Bp fp8 + c2s = ||c||^2+1024 ----
__global__ __launch_bounds__(256) void prep(const float* __restrict__ x,
                                            const float* __restrict__ cb,
                                            uint8_t* __restrict__ Ap,
                                            uint8_t* __restrict__ Bp,
                                            float* __restrict__ c2s,
                                            float* __restrict__ out_ze) {
  const int w = threadIdx.x >> 6, lane = threadIdx.x & 63;
  if (blockIdx.x < M_ROWS / 4) {
    const int row = blockIdx.x * 4 + w;                 // one wave per x row
    const f32x4 v = *(const f32x4*)(x + (size_t)row * D_DIM + lane * 4);
    // store -2x: exact (sign+exponent), q(-2x)q(c) == -2 q(x)q(c) bit-exact,
    // so the EPS error bound is unchanged. |2x| <= ~11 << 448 (e4m3 max).
    f32x4 nv;
#pragma unroll
    for (int t = 0; t < 4; ++t) nv[t] = -2.0f * v[t];
    *(uint32_t*)(Ap + (size_t)row * D_DIM + lane * 4) = fp8x4(nv);
    *(f32x4*)(out_ze + (size_t)row * D_DIM + lane * 4) = v;   // identity encoder
  } else {
    const int row = (blockIdx.x - M_ROWS / 4) * 4 + w;  // one wave per codeword
    const f32x4 v = *(const f32x4*)(cb + (size_t)row * D_DIM + lane * 4);
    *(uint32_t*)(Bp + (size_t)row * D_DIM + lane * 4) = fp8x4(v);
    double s = 0.0;
#pragma unroll
    for (int t = 0; t < 4; ++t) s += (double)v[t] * (double)v[t];
#pragma unroll
    for (int m = 1; m < 64; m <<= 1) s += __shfl_xor(s, m, 64);
    if (lane == 0) c2s[row] = (float)s + 1024.0f;       // pre-shifted: s>0 packing
  }
}

// ---- main: fp8 K=256 GEMM, DMA-pipelined LDS B, fused packed top-4/split ----
__global__ __launch_bounds__(256, 3) void vq_main(const uint8_t* __restrict__ Ap,
                                                  const uint8_t* __restrict__ Bp,
                                                  const float* __restrict__ c2s,
                                                  uint4* __restrict__ part) {
  __shared__ uint8_t Bs[2][CHUNK * D_DIM];   // 2 x 16 KB, chunk-swizzled

  const int w    = threadIdx.x >> 6;
  const int lane = threadIdx.x & 63;
  const int fr   = lane & 15;         // frag m/n index
  const int fq   = lane >> 4;         // frag k-quarter (32 contiguous bytes)

  const int rowBase = blockIdx.x * 128 + w * 32;        // wave owns 32 rows
  const int colBase = blockIdx.y * 512;                 // block owns one split

  // A fragments (-2x) for the whole kernel
  int8v af[2][2];
  {
    const uint8_t* ab = Ap + (size_t)(rowBase + fr) * D_DIM + fq * 32;
#pragma unroll
    for (int i = 0; i < 2; ++i)
#pragma unroll
      for (int kh = 0; kh < 2; ++kh)
        af[i][kh] = *(const int8v*)(ab + (size_t)(i * 16) * D_DIM + kh * 128);
  }

  // stage-invariant DMA offsets: row rr = ii*4+dRow within the wave's 16 rows;
  // phys 16B chunk p of row n holds logical chunk p^(n&15), applied on the
  // GLOBAL source address (gld dest is wave-uniform base + lane*16).
  const int dRow = lane >> 4;
  const int dChk = lane & 15;
  int goff[4];
#pragma unroll
  for (int ii = 0; ii < 4; ++ii) {
    const int rr = ii * 4 + dRow;                       // == row & 15
    goff[ii] = rr * D_DIM + ((dChk ^ rr) << 4);
  }

#define STAGE_DMA(c, buf)                                                      \
  {                                                                            \
    const uint8_t* gb = Bp + ((size_t)(colBase + (c) * CHUNK + w * 16) << 8);  \
    uint8_t* lb = &Bs[buf][w * 16 * D_DIM] + lane * 16;                        \
    _Pragma("unroll")                                                          \
    for (int ii = 0; ii < 4; ++ii)                                             \
      gld_lds16(gb + goff[ii], lb + ii * 4 * D_DIM);                           \
  }

  // sorted top-4 per slot [i][r], packed ((s+1024) bits & ~511) | col9
  uint32_t t1[2][4], t2[2][4], t3[2][4], t4[2][4];
#pragma unroll
  for (int i = 0; i < 2; ++i)
#pragma unroll
    for (int r = 0; r < 4; ++r) {
      t1[i][r] = 0x7f7ffe00u; t2[i][r] = 0x7f7ffe00u;
      t3[i][r] = 0x7f7ffe00u; t4[i][r] = 0x7f7ffe00u;
    }

  // 1-stage-ahead rotating c2 prefetch: cvc = stage c (consumed now),
  // cvn = stage c+1 (issued right after the barrier, consumed ~600cy later).
  const float* c2p = c2s + colBase + fr;
  float cvc[4], cvn[4];
#pragma unroll
  for (int jj = 0; jj < 4; ++jj) cvc[jj] = c2p[jj * 16];

  // per-lane loop-invariant LDS byte-offsets (XORs stay below fr*256, no
  // carry): full read addr = Bs[c&1] + aK + jj*4096, jj*4096 -> offset imm.
  const int y0 = (fq * 2) << 4;                         // logical 32B k-quarter
  const int a0 = fr * D_DIM + (y0 ^ (fr << 4));         // kh=0 lo
  const int a1 = a0 ^ 16;                               // kh=0 hi
  const int a2 = a0 ^ 128;                              // kh=1 lo
  const int a3 = a0 ^ 144;                              // kh=1 hi

  STAGE_DMA(0, 0);

  for (int c = 0; c < 512 / CHUNK; ++c) {               // 8 stages, rolled
    __syncthreads();              // DMA[c] landed (issued a full stage ago)
    if (c < 512 / CHUNK - 1) {
      STAGE_DMA(c + 1, (c + 1) & 1);
#pragma unroll
      for (int jj = 0; jj < 4; ++jj)                    // prefetch next c2
        cvn[jj] = c2p[(c + 1) * CHUNK + jj * 16];
    }

    const uint8_t* bsb = Bs[c & 1];
    const int cb0 = c * CHUNK;

#pragma unroll
    for (int jj = 0; jj < 4; ++jj) {                    // 4 col-frags of 16
      const int4v lo0 = *(const int4v*)(bsb + a0 + jj * 4096);
      const int4v hi0 = *(const int4v*)(bsb + a1 + jj * 4096);
      const int4v lo1 = *(const int4v*)(bsb + a2 + jj * 4096);
      const int4v hi1 = *(const int4v*)(bsb + a3 + jj * 4096);
      const int8v bf0 = __builtin_shufflevector(lo0, hi0, 0, 1, 2, 3, 4, 5, 6, 7);
      const int8v bf1 = __builtin_shufflevector(lo1, hi1, 0, 1, 2, 3, 4, 5, 6, 7);

      const float cv = cvc[jj];
      const f32x4 cvv4 = (f32x4){cv, cv, cv, cv};       // shared C operand
      // c2 enters through C; C is read-only when D != C, so both i-chains
      // start from the SAME cvv4 (halves acc-init movs vs two acc copies).
      f32x4 t0 = __builtin_amdgcn_mfma_scale_f32_16x16x128_f8f6f4(
          af[0][0], bf0, cvv4, 0, 0, 0, 0x7f7f7f7f, 0, 0x7f7f7f7f);
      f32x4 acc0 = __builtin_amdgcn_mfma_scale_f32_16x16x128_f8f6f4(
          af[0][1], bf1, t0, 0, 0, 0, 0x7f7f7f7f, 0, 0x7f7f7f7f);
      f32x4 t1v = __builtin_amdgcn_mfma_scale_f32_16x16x128_f8f6f4(
          af[1][0], bf0, cvv4, 0, 0, 0, 0x7f7f7f7f, 0, 0x7f7f7f7f);
      f32x4 acc1 = __builtin_amdgcn_mfma_scale_f32_16x16x128_f8f6f4(
          af[1][1], bf1, t1v, 0, 0, 0, 0x7f7f7f7f, 0, 0x7f7f7f7f);

      // epilogue: acc == s = (1024+c2) - 2*cross; pack; med3 top-4 insert
      const int col9 = cb0 + jj * 16 + fr;
#pragma unroll
      for (int r = 0; r < 4; ++r) {
        const uint32_t p0 = (__float_as_uint(acc0[r]) & ~511u) | (uint32_t)col9;
        const uint32_t o1 = t1[0][r], o2 = t2[0][r];
        const uint32_t o3 = t3[0][r], o4 = t4[0][r];
        t1[0][r] = fmin32(p0, o1);                  // 4 independent ops,
        t2[0][r] = fmed32(p0, o1, o2);              // no serial chain
        t3[0][r] = fmed32(p0, o2, o3);
        t4[0][r] = fmed32(p0, o3, o4);
        const uint32_t p1 = (__float_as_uint(acc1[r]) & ~511u) | (uint32_t)col9;
        const uint32_t q1 = t1[1][r], q2 = t2[1][r];
        const uint32_t q3 = t3[1][r], q4 = t4[1][r];
        t1[1][r] = fmin32(p1, q1);
        t2[1][r] = fmed32(p1, q1, q2);
        t3[1][r] = fmed32(p1, q2, q3);
        t4[1][r] = fmed32(p1, q3, q4);
      }
    }

    if (c < 512 / CHUNK - 1) {
#pragma unroll
      for (int jj = 0; jj < 4; ++jj) cvc[jj] = cvn[jj]; // rotate (4 v_mov)
    }
  }

  // cross-fr bitonic merge (lanes with same fq hold the same rows, disjoint
  // cols); lane fr==0 of each fq then stores its rows' top-4 directly.
#pragma unroll
  for (int i = 0; i < 2; ++i)
#pragma unroll
    for (int r = 0; r < 4; ++r) {
      uint32_t a1_ = t1[i][r], a2_ = t2[i][r], a3_ = t3[i][r], a4_ = t4[i][r];
#pragma unroll
      for (int m = 1; m < 16; m <<= 1) {
        const uint32_t b1 = __shfl_xor(a1_, m, 64);
        const uint32_t b2 = __shfl_xor(a2_, m, 64);
        const uint32_t b3 = __shfl_xor(a3_, m, 64);
        const uint32_t b4 = __shfl_xor(a4_, m, 64);
        uint32_t c1 = umin32(a1_, b4), c2_ = umin32(a2_, b3);
        uint32_t c3 = umin32(a3_, b2), c4 = umin32(a4_, b1);
        uint32_t lo, hi;
        lo = umin32(c1, c3); hi = umax32(c1, c3); c1 = lo; c3 = hi;
        lo = umin32(c2_, c4); hi = umax32(c2_, c4); c2_ = lo; c4 = hi;
        lo = umin32(c1, c2_); hi = umax32(c1, c2_); c1 = lo; c2_ = hi;
        lo = umin32(c3, c4); hi = umax32(c3, c4); c3 = lo; c4 = hi;
        a1_ = c1; a2_ = c2_; a3_ = c3; a4_ = c4;
      }
      if (fr == 0) {
        const int row = rowBase + i * 16 + fq * 4 + r;   // C/D layout (m89)
        part[(size_t)row * NSPLIT + blockIdx.y] = make_uint4(a1_, a2_, a3_, a4_);
      }
    }
}

// -------- merge: 64 candidates/row -> certain winner or fp64 rescore --------
__global__ __launch_bounds__(256) void vq_merge(const uint32_t* __restrict__ part,
                                                const float* __restrict__ x,
                                                const float* __restrict__ cb,
                                                float* __restrict__ out) {
  const int w = threadIdx.x >> 6, lane = threadIdx.x & 63;
  const int row = blockIdx.x * 4 + w;                 // one wave per row

  const uint32_t pk = part[(size_t)row * 64 + lane];  // coalesced, 1 cand/lane
  const int gidx = (lane >> 2) * (K_CB / NSPLIT) + (int)(pk & 511u);

  // integer min == numeric min (all packed values positive)
  uint32_t pmin = pk;
#pragma unroll
  for (int m = 1; m < 64; m <<= 1) {
    const uint32_t o = __shfl_xor(pmin, m, 64);
    pmin = pmin < o ? pmin : o;
  }
  const float vmin = __uint_as_float(pmin & ~511u);
  const float vme  = __uint_as_float(pk & ~511u);
  const unsigned long long mask = __ballot(vme <= vmin + EPS);

  int winner;
  if (__popcll(mask) == 1) {
    winner = __shfl(gidx, __ffsll((long long)mask) - 1, 64);
  } else {
    // exact fp64 rescore of the qualifiers (ties -> smaller index, like np)
    const f32x4 xv = *(const f32x4*)(x + (size_t)row * D_DIM + lane * 4);
    double bestd = 1.0e300;
    int bidx = 0x7fffffff;
    unsigned long long mm = mask;
    while (mm) {
      const int q = __ffsll((long long)mm) - 1;
      mm &= mm - 1;
      const int ci = __shfl(gidx, q, 64);
      const f32x4 cv = *(const f32x4*)(cb + (size_t)ci * D_DIM + lane * 4);
      double s = 0.0;
#pragma unroll
      for (int t = 0; t < 4; ++t) {
        const double dx = (double)xv[t] - (double)cv[t];
        s += dx * dx;
      }
#pragma unroll
      for (int m = 1; m < 64; m <<= 1) s += __shfl_xor(s, m, 64);
      if (s < bestd || (s == bestd && ci < bidx)) { bestd = s; bidx = ci; }
    }
    winner = bidx;
  }

  float* out_recon = out;                               // out_ze written by prep
  float* out_zq    = out + 2 * (size_t)M_ROWS * D_DIM;
  float* out_idx   = out + 3 * (size_t)M_ROWS * D_DIM;

  const f32x4 cv = *(const f32x4*)(cb + (size_t)winner * D_DIM + lane * 4);
  *(f32x4*)(out_recon + (size_t)row * D_DIM + lane * 4) = cv;  // identity decoder
  *(f32x4*)(out_zq    + (size_t)row * D_DIM + lane * 4) = cv;
  if (lane == 0) out_idx[row] = (float)winner;
}

extern "C" void kernel_launch(void* const* d_in, const int* in_sizes, int n_in,
                              void* d_out, int out_size, void* d_ws, size_t ws_size,
                              hipStream_t stream) {
  const float* x  = (const float*)d_in[0];
  const float* cb = (const float*)d_in[1];
  float* out = (float*)d_out;

  // ws: c2s 32 KB | part uint4[16384][16] 4 MB | Ap fp8 4 MB | Bp fp8 2 MB | pad
  char* ws = (char*)d_ws;
  float*    c2s  = (float*)ws;
  uint4*    part = (uint4*)(ws + 32768);
  uint8_t*  Ap   = (uint8_t*)(ws + 32768 + 4194304);
  uint8_t*  Bp   = Ap + (size_t)M_ROWS * D_DIM;
  if (ws_size < (size_t)(32768 + 4194304 + 4194304 + 2097152 + 4096)) return;

  float* out_ze = out + (size_t)M_ROWS * D_DIM;

  prep    <<<dim3(M_ROWS / 4 + K_CB / 4), dim3(256), 0, stream>>>(x, cb, Ap, Bp, c2s, out_ze);
  vq_main <<<dim3(M_ROWS / 128, NSPLIT), dim3(256), 0, stream>>>(Ap, Bp, c2s, part);
  vq_merge<<<dim3(M_ROWS / 4), dim3(256), 0, stream>>>((const uint32_t*)part, x, cb, out);
}